// Round 3
// baseline (844.611 us; speedup 1.0000x reference)
//
#include <hip/hip_runtime.h>
#include <hip/hip_bf16.h>

// CGConv fused for MI355X (gfx950) — round 8.
//   gemm: B split across 6 waves of a 384-thread block. Wave w holds the
//         col-pair {gate tile w, msg tile w+6} = 16 B-frags = 64 VGPR, so
//         total VGPR ~130 -> 3 waves/SIMD (vs round 7's 1 wave/SIMD which
//         exposed all gather latency, and round 5's 2.4 GB/kernel of L2
//         B-traffic). All 6 waves chew the same 32-edge tile (A re-reads hit
//         per-CU L1); 2048 persistent blocks grid-stride so B is preloaded
//         once per block (196 MB total, 12x less B traffic than round 5).
//         rank[] prefetched at loop top; next tile's eidx prefetched under
//         the MFMAs. Memory-stream geometry (hb gather / ea stream / msg
//         scatter window) intentionally matches round 5.
//   CSR:  scatter produces inverse-perm rank[e]; gemm writes msg rows directly
//         at CSR position -> aggregate is a contiguous vectorized stream.

#define NODE_DIM 96
#define EDGE_DIM 64
#define IN_DIM   256
#define NT_TILES 12       // 192 output cols = 96 gates + 96 msgs
#define KT_TILES 8        // 256 / 32

#define GEMM_GRID   2048  // persistent blocks, grid-stride over 32-edge tiles
#define GEMM_WAVES  6
#define GEMM_THREADS (GEMM_WAVES * 64)

typedef float  f32x4  __attribute__((ext_vector_type(4)));
typedef __bf16 bf16x8 __attribute__((ext_vector_type(8)));

__device__ __forceinline__ unsigned short bf16rne(float f) {
    unsigned int u = __float_as_uint(f);
    u += 0x7FFFu + ((u >> 16) & 1u);
    return (unsigned short)(u >> 16);
}

// ---------------------------------------------------------------------------
// Pack W_e/W_n (256x96 fp32 row-major) into bf16 MFMA B-fragment order.
// ---------------------------------------------------------------------------
__global__ void pack_w_kernel(const float* __restrict__ We,
                              const float* __restrict__ Wn,
                              unsigned short* __restrict__ bpack) {
    int t = blockIdx.x * blockDim.x + threadIdx.x;
    if (t >= KT_TILES * NT_TILES * 64) return;
    int tile = t >> 6, lane = t & 63;
    int kt = tile / NT_TILES, nt = tile % NT_TILES;
    const float* W = (nt < 6) ? We : Wn;
    int n  = (nt % 6) * 16 + (lane & 15);
    int k0 = kt * 32 + (lane >> 4) * 8;
    union { unsigned short u[8]; uint4 v; } tmp;
#pragma unroll
    for (int j = 0; j < 8; ++j) tmp.u[j] = bf16rne(W[(k0 + j) * NODE_DIM + n]);
    *(uint4*)(bpack + (size_t)t * 8) = tmp.v;
}

// ---------------------------------------------------------------------------
// h (N x 96 fp32) -> hb (N x 96 bf16)
// ---------------------------------------------------------------------------
__global__ void cvt_h_kernel(const float* __restrict__ h,
                             unsigned short* __restrict__ hb, int total8) {
    int i = blockIdx.x * 256 + threadIdx.x;
    if (i >= total8) return;
    const float4 v0 = ((const float4*)h)[i * 2];
    const float4 v1 = ((const float4*)h)[i * 2 + 1];
    union { unsigned short u[8]; uint4 v; } p;
    p.u[0] = bf16rne(v0.x); p.u[1] = bf16rne(v0.y);
    p.u[2] = bf16rne(v0.z); p.u[3] = bf16rne(v0.w);
    p.u[4] = bf16rne(v1.x); p.u[5] = bf16rne(v1.y);
    p.u[6] = bf16rne(v1.z); p.u[7] = bf16rne(v1.w);
    ((uint4*)hb)[i] = p.v;
}

// ---------------------------------------------------------------------------
// CSR build: histogram -> exclusive scan -> rank (inverse permutation)
// ---------------------------------------------------------------------------
__global__ void hist_kernel(const int* __restrict__ eidx, unsigned* __restrict__ deg, int E) {
    int e = blockIdx.x * 256 + threadIdx.x;
    if (e < E) atomicAdd(deg + eidx[E + e], 1u);
}

__device__ __forceinline__ unsigned block_excl_scan_256(unsigned v, int tid,
                                                        unsigned* wsum, unsigned* wpre,
                                                        unsigned* total) {
    int lane = tid & 63, w = tid >> 6;
    unsigned inc = v;
#pragma unroll
    for (int o = 1; o < 64; o <<= 1) {
        unsigned t = __shfl_up(inc, o, 64);
        if (lane >= o) inc += t;
    }
    if (lane == 63) wsum[w] = inc;
    __syncthreads();
    if (tid == 0) {
        unsigned s = 0;
#pragma unroll
        for (int k = 0; k < 4; ++k) { wpre[k] = s; s += wsum[k]; }
        *total = s;
    }
    __syncthreads();
    return inc - v + wpre[w];
}

__global__ void scan_block_kernel(const unsigned* __restrict__ deg,
                                  unsigned* __restrict__ scanned,
                                  unsigned* __restrict__ blocksum, int N) {
    __shared__ unsigned wsum[4], wpre[4], total;
    int tid = threadIdx.x;
    int i = blockIdx.x * 256 + tid;
    unsigned v = (i < N) ? deg[i] : 0u;
    unsigned excl = block_excl_scan_256(v, tid, wsum, wpre, &total);
    if (i < N) scanned[i] = excl;
    if (tid == 0) blocksum[blockIdx.x] = total;
}

__global__ void scan_sums_kernel(const unsigned* __restrict__ blocksum,
                                 unsigned* __restrict__ blockpref, int NB) {
    __shared__ unsigned wsum[4], wpre[4], total;
    int tid = threadIdx.x;
    unsigned v = (tid < NB) ? blocksum[tid] : 0u;
    unsigned excl = block_excl_scan_256(v, tid, wsum, wpre, &total);
    if (tid < NB) blockpref[tid] = excl;
}

__global__ void scan_finalize_kernel(const unsigned* __restrict__ scanned,
                                     const unsigned* __restrict__ blockpref,
                                     unsigned* __restrict__ offsets,
                                     unsigned* __restrict__ cursor, int N, int E) {
    int i = blockIdx.x * 256 + threadIdx.x;
    if (i < N) {
        unsigned o = scanned[i] + blockpref[i >> 8];
        offsets[i] = o;
        cursor[i]  = o;
    }
    if (i == 0) offsets[N] = (unsigned)E;
}

__global__ void scatter_kernel(const int* __restrict__ eidx,
                               unsigned* __restrict__ cursor,
                               unsigned* __restrict__ rank, int E) {
    int e = blockIdx.x * 256 + threadIdx.x;
    if (e < E) {
        int d = eidx[E + e];
        rank[e] = atomicAdd(cursor + d, 1u);
    }
}

// ---------------------------------------------------------------------------
// Pass B: per-edge GEMM + activation -> bf16 msg at CSR position rank[e].
// 384-thread blocks (6 waves). Wave w owns output col-pair {nt=w, nt=w+6}:
// its 16 B-fragments (64 VGPR) are preloaded once; the grid-stride loop over
// 32-edge tiles has ZERO B loads. All waves share the tile's A data via L1.
// ---------------------------------------------------------------------------
__global__ __launch_bounds__(GEMM_THREADS, 3)
void gemm_msg_kernel(const unsigned short* __restrict__ hb,
                     const int*   __restrict__ eidx,
                     const float* __restrict__ ea,
                     const unsigned short* __restrict__ bpack,
                     const float* __restrict__ be,
                     const float* __restrict__ bn,
                     const unsigned* __restrict__ rank,
                     unsigned short* __restrict__ msg,
                     int E) {
    const int tid  = threadIdx.x;
    const int wave = tid >> 6, lane = tid & 63;
    const int m    = lane & 15;
    const int quad = lane >> 4;

    // ---- preload this wave's B col-pair: 16 frags = 64 VGPR ----
    bf16x8 Bg[KT_TILES], Bm[KT_TILES];
    {
        const bf16x8* bp = (const bf16x8*)bpack + lane;
#pragma unroll
        for (int kt = 0; kt < KT_TILES; ++kt) {
            Bg[kt] = bp[(kt * NT_TILES + wave) * 64];
            Bm[kt] = bp[(kt * NT_TILES + wave + 6) * 64];
        }
    }
    const int   col = wave * 16 + m;
    const float bev = be[col];
    const float bnv = bn[col];

    // prime first tile's edge indices
    int csrc[2], cdst[2], nsrc[2], ndst[2];
#pragma unroll
    for (int mt = 0; mt < 2; ++mt) {
        int e  = blockIdx.x * 32 + mt * 16 + m;
        int eg = (e < E) ? e : (E - 1);
        csrc[mt] = eidx[eg];
        cdst[mt] = eidx[E + eg];
    }

    for (int t = blockIdx.x; (long)t * 32 < E; t += GEMM_GRID) {
        const int base = t * 32;

        const unsigned short* hsq[2];
        const unsigned short* hdq[2];
        const float*          epq[2];
#pragma unroll
        for (int mt = 0; mt < 2; ++mt) {
            int e  = base + mt * 16 + m;
            int eg = (e < E) ? e : (E - 1);
            hsq[mt] = hb + (size_t)csrc[mt] * NODE_DIM + quad * 8;
            hdq[mt] = hb + (size_t)cdst[mt] * NODE_DIM + quad * 8;
            epq[mt] = ea + (size_t)eg  * EDGE_DIM + quad * 8;
        }

        // prefetch rank rows for this tile's epilogue (independent loads)
        unsigned prow_[2][4];
#pragma unroll
        for (int mt = 0; mt < 2; ++mt)
#pragma unroll
            for (int r = 0; r < 4; ++r) {
                int ee = base + mt * 16 + quad * 4 + r;
                prow_[mt][r] = rank[(ee < E) ? ee : (E - 1)];
            }

        // prefetch next tile's edge indices (hidden under the MFMAs)
        const int tn = t + GEMM_GRID;
        if ((long)tn * 32 < E) {
#pragma unroll
            for (int mt = 0; mt < 2; ++mt) {
                int e  = tn * 32 + mt * 16 + m;
                int eg = (e < E) ? e : (E - 1);
                nsrc[mt] = eidx[eg];
                ndst[mt] = eidx[E + eg];
            }
        }

        f32x4 accg[2], accm[2];
#pragma unroll
        for (int mt = 0; mt < 2; ++mt) {
            accg[mt] = (f32x4){0.f, 0.f, 0.f, 0.f};
            accm[mt] = (f32x4){0.f, 0.f, 0.f, 0.f};
        }

#pragma unroll
        for (int kt = 0; kt < KT_TILES; ++kt) {
            bf16x8 A[2];
#pragma unroll
            for (int mt = 0; mt < 2; ++mt) {
                if (kt < 3) {
                    A[mt] = *(const bf16x8*)(hsq[mt] + kt * 32);
                } else if (kt < 6) {
                    A[mt] = *(const bf16x8*)(hdq[mt] + (kt - 3) * 32);
                } else {
                    const float4 v0 = *(const float4*)(epq[mt] + (kt - 6) * 32);
                    const float4 v1 = *(const float4*)(epq[mt] + (kt - 6) * 32 + 4);
                    union { unsigned short u[8]; bf16x8 b; } tt;
                    tt.u[0] = bf16rne(v0.x); tt.u[1] = bf16rne(v0.y);
                    tt.u[2] = bf16rne(v0.z); tt.u[3] = bf16rne(v0.w);
                    tt.u[4] = bf16rne(v1.x); tt.u[5] = bf16rne(v1.y);
                    tt.u[6] = bf16rne(v1.z); tt.u[7] = bf16rne(v1.w);
                    A[mt] = tt.b;
                }
            }
#pragma unroll
            for (int mt = 0; mt < 2; ++mt) {
                accg[mt] = __builtin_amdgcn_mfma_f32_16x16x32_bf16(A[mt], Bg[kt], accg[mt], 0, 0, 0);
                accm[mt] = __builtin_amdgcn_mfma_f32_16x16x32_bf16(A[mt], Bm[kt], accm[mt], 0, 0, 0);
            }
        }

        // epilogue: wave writes its 16 cols for the 32 edges
#pragma unroll
        for (int mt = 0; mt < 2; ++mt) {
#pragma unroll
            for (int r = 0; r < 4; ++r) {
                const int ee = base + mt * 16 + quad * 4 + r;
                if (ee >= E) continue;
                float g  = accg[mt][r] + bev;
                float mm = accm[mt][r] + bnv;
                float gate = 1.0f / (1.0f + __expf(-g));
                float sp   = fmaxf(mm, 0.0f) + __logf(1.0f + __expf(-fabsf(mm)));
                msg[(size_t)prow_[mt][r] * NODE_DIM + col] = bf16rne(gate * sp);
            }
        }

#pragma unroll
        for (int mt = 0; mt < 2; ++mt) { csrc[mt] = nsrc[mt]; cdst[mt] = ndst[mt]; }
    }
}

// ---------------------------------------------------------------------------
// Pass C: streaming CSR reduce. Thread = (node, 8-col group): 12 threads/node,
// 16B loads, rows contiguous at offsets[n]..offsets[n+1].
// ---------------------------------------------------------------------------
__global__ __launch_bounds__(256)
void aggregate_kernel(const float* __restrict__ h,
                      const unsigned* __restrict__ offsets,
                      const unsigned short* __restrict__ msg,
                      float* __restrict__ out, int N) {
    int t = blockIdx.x * 256 + threadIdx.x;
    int n = t / 12, g = t % 12;
    if (n >= N) return;

    const unsigned o0 = offsets[n];
    const unsigned o1 = offsets[n + 1];
    const int deg = (int)(o1 - o0);

    float s0 = 0.f, s1 = 0.f, s2 = 0.f, s3 = 0.f;
    float s4 = 0.f, s5 = 0.f, s6 = 0.f, s7 = 0.f;
    for (unsigned k = o0; k < o1; ++k) {
        const uint4 v = *(const uint4*)(msg + (size_t)k * NODE_DIM + g * 8);
        s0 += __uint_as_float((v.x & 0xFFFFu) << 16);
        s1 += __uint_as_float(v.x & 0xFFFF0000u);
        s2 += __uint_as_float((v.y & 0xFFFFu) << 16);
        s3 += __uint_as_float(v.y & 0xFFFF0000u);
        s4 += __uint_as_float((v.z & 0xFFFFu) << 16);
        s5 += __uint_as_float(v.z & 0xFFFF0000u);
        s6 += __uint_as_float((v.w & 0xFFFFu) << 16);
        s7 += __uint_as_float(v.w & 0xFFFF0000u);
    }
    const float inv = 1.0f / (float)((deg > 0) ? deg : 1);
    const size_t basei = (size_t)n * NODE_DIM + g * 8;
    const float4 h0 = *(const float4*)(h + basei);
    const float4 h1 = *(const float4*)(h + basei + 4);
    float4 o0v = {h0.x + s0 * inv, h0.y + s1 * inv, h0.z + s2 * inv, h0.w + s3 * inv};
    float4 o1v = {h1.x + s4 * inv, h1.y + s5 * inv, h1.z + s6 * inv, h1.w + s7 * inv};
    *(float4*)(out + basei)     = o0v;
    *(float4*)(out + basei + 4) = o1v;
}

// ---------------------------------------------------------------------------
// Fallback (atomic path) if workspace is too small for the CSR pipeline.
// ---------------------------------------------------------------------------
#define TILE_E 64
__global__ __launch_bounds__(256, 4)
void cgconv_atomic_kernel(const float* __restrict__ h,
                          const int*   __restrict__ eidx,
                          const float* __restrict__ ea,
                          const unsigned short* __restrict__ bpack,
                          const float* __restrict__ be,
                          const float* __restrict__ bn,
                          float* __restrict__ hnew,
                          float* __restrict__ cnt,
                          int E) {
    const int tid  = threadIdx.x;
    const int wave = tid >> 6, lane = tid & 63;
    const int m    = lane & 15;
    const int quad = lane >> 4;

    const int e  = blockIdx.x * TILE_E + wave * 16 + m;
    const int eg = (e < E) ? e : (E - 1);
    const int src = eidx[eg];
    const int dst = eidx[E + eg];
    if (quad == 0 && e < E) unsafeAtomicAdd(cnt + dst, 1.0f);

    f32x4 acc[NT_TILES];
#pragma unroll
    for (int nt = 0; nt < NT_TILES; ++nt) acc[nt] = (f32x4){0.f, 0.f, 0.f, 0.f};

    const float* hsrc = h + (size_t)src * NODE_DIM;
    const float* hdst = h + (size_t)dst * NODE_DIM;
    const float* earo = ea + (size_t)eg * EDGE_DIM;

#pragma unroll
    for (int kt = 0; kt < KT_TILES; ++kt) {
        const int ko = kt * 32 + quad * 8;
        const float* p;
        if (kt < 3)      p = hsrc + ko;
        else if (kt < 6) p = hdst + (ko - NODE_DIM);
        else             p = earo + (ko - 2 * NODE_DIM);
        const float4 v0 = *(const float4*)p;
        const float4 v1 = *(const float4*)(p + 4);
        union { unsigned short u[8]; bf16x8 b; } A;
        A.u[0] = bf16rne(v0.x); A.u[1] = bf16rne(v0.y);
        A.u[2] = bf16rne(v0.z); A.u[3] = bf16rne(v0.w);
        A.u[4] = bf16rne(v1.x); A.u[5] = bf16rne(v1.y);
        A.u[6] = bf16rne(v1.z); A.u[7] = bf16rne(v1.w);
#pragma unroll
        for (int nt = 0; nt < NT_TILES; ++nt) {
            bf16x8 bfrag = *(const bf16x8*)(bpack +
                             (size_t)((kt * NT_TILES + nt) * 64 + lane) * 8);
            acc[nt] = __builtin_amdgcn_mfma_f32_16x16x32_bf16(A.b, bfrag, acc[nt], 0, 0, 0);
        }
    }

    int drow[4], erow[4];
#pragma unroll
    for (int r = 0; r < 4; ++r) {
        drow[r] = __shfl(dst, quad * 4 + r, 64);
        erow[r] = blockIdx.x * TILE_E + wave * 16 + quad * 4 + r;
    }
#pragma unroll
    for (int nt = 0; nt < 6; ++nt) {
        const int col = nt * 16 + m;
        const float bev = be[col];
        const float bnv = bn[col];
#pragma unroll
        for (int r = 0; r < 4; ++r) {
            if (erow[r] >= E) continue;
            float g  = acc[nt][r] + bev;
            float mm = acc[nt + 6][r] + bnv;
            float gate = 1.0f / (1.0f + __expf(-g));
            float sp   = fmaxf(mm, 0.0f) + __logf(1.0f + __expf(-fabsf(mm)));
            unsafeAtomicAdd(hnew + (size_t)drow[r] * NODE_DIM + col, gate * sp);
        }
    }
}

__global__ void finalize_kernel(const float* __restrict__ h,
                                const float* __restrict__ hnew,
                                const float* __restrict__ cnt,
                                float* __restrict__ out,
                                int total4) {
    int i = blockIdx.x * blockDim.x + threadIdx.x;
    if (i >= total4) return;
    int n = i / 24;
    float inv = 1.0f / fmaxf(cnt[n], 1.0f);
    float4 hv = ((const float4*)h)[i];
    float4 av = ((const float4*)hnew)[i];
    float4 o = {hv.x + av.x * inv, hv.y + av.y * inv, hv.z + av.z * inv, hv.w + av.w * inv};
    ((float4*)out)[i] = o;
}

// ---------------------------------------------------------------------------
extern "C" void kernel_launch(void* const* d_in, const int* in_sizes, int n_in,
                              void* d_out, int out_size, void* d_ws, size_t ws_size,
                              hipStream_t stream) {
    const float* h   = (const float*)d_in[0];
    const int*   ei  = (const int*)  d_in[1];
    const float* ea  = (const float*)d_in[2];
    const float* We  = (const float*)d_in[3];
    const float* be  = (const float*)d_in[4];
    const float* Wn  = (const float*)d_in[5];
    const float* bn  = (const float*)d_in[6];

    const int N = in_sizes[0] / NODE_DIM;     // 50000
    const int E = in_sizes[2] / EDGE_DIM;     // 800000
    char* ws = (char*)d_ws;

    size_t off = 0;
    auto take = [&](size_t bytes) { size_t o = off; off = (off + bytes + 511) & ~(size_t)511; return o; };
    const size_t O_BPACK  = take((size_t)KT_TILES * NT_TILES * 64 * 16);   // 96 KB
    const size_t O_DEG    = take((size_t)N * 4);
    const size_t O_SCAN   = take((size_t)N * 4);
    const size_t O_BSUM   = take(1024);
    const size_t O_BPREF  = take(1024);
    const size_t O_OFFS   = take((size_t)(N + 1) * 4);
    const size_t O_CURS   = take((size_t)N * 4);
    const size_t O_RANK   = take((size_t)E * 4);
    const size_t O_HB     = take((size_t)N * NODE_DIM * 2);               // 9.6 MB
    const size_t O_MSG    = take((size_t)E * NODE_DIM * 2);               // 153.6 MB
    const size_t NEED = off;

    unsigned short* bpack = (unsigned short*)(ws + O_BPACK);
    pack_w_kernel<<<(KT_TILES * NT_TILES * 64 + 255) / 256, 256, 0, stream>>>(We, Wn, bpack);

    if (ws_size >= NEED) {
        unsigned* deg    = (unsigned*)(ws + O_DEG);
        unsigned* scn    = (unsigned*)(ws + O_SCAN);
        unsigned* bsum   = (unsigned*)(ws + O_BSUM);
        unsigned* bpref  = (unsigned*)(ws + O_BPREF);
        unsigned* offs   = (unsigned*)(ws + O_OFFS);
        unsigned* curs   = (unsigned*)(ws + O_CURS);
        unsigned* rank   = (unsigned*)(ws + O_RANK);
        unsigned short* hb  = (unsigned short*)(ws + O_HB);
        unsigned short* msg = (unsigned short*)(ws + O_MSG);

        hipMemsetAsync(deg, 0, (size_t)N * 4, stream);

        const int total8 = N * NODE_DIM / 8;   // 600000
        cvt_h_kernel<<<(total8 + 255) / 256, 256, 0, stream>>>(h, hb, total8);

        const int NB = (N + 255) / 256;
        hist_kernel<<<(E + 255) / 256, 256, 0, stream>>>(ei, deg, E);
        scan_block_kernel<<<NB, 256, 0, stream>>>(deg, scn, bsum, N);
        scan_sums_kernel<<<1, 256, 0, stream>>>(bsum, bpref, NB);
        scan_finalize_kernel<<<NB, 256, 0, stream>>>(scn, bpref, offs, curs, N, E);
        scatter_kernel<<<(E + 255) / 256, 256, 0, stream>>>(ei, curs, rank, E);

        gemm_msg_kernel<<<GEMM_GRID, GEMM_THREADS, 0, stream>>>(hb, ei, ea, bpack, be, bn, rank, msg, E);

        const int aggthreads = N * 12;
        aggregate_kernel<<<(aggthreads + 255) / 256, 256, 0, stream>>>(h, offs, msg, (float*)d_out, N);
    } else {
        size_t cnt_off  = O_DEG;
        size_t hnew_off = (cnt_off + (size_t)N * 4 + 511) & ~(size_t)511;
        float* cnt  = (float*)(ws + cnt_off);
        float* hnew = (float*)(ws + hnew_off);
        hipMemsetAsync(ws + cnt_off, 0, hnew_off - cnt_off + (size_t)N * NODE_DIM * 4, stream);
        cgconv_atomic_kernel<<<(E + TILE_E - 1) / TILE_E, 256, 0, stream>>>(
            h, ei, ea, bpack, be, bn, hnew, cnt, E);
        const int total4 = N * (NODE_DIM / 4);
        finalize_kernel<<<(total4 + 255) / 256, 256, 0, stream>>>(h, hnew, cnt, (float*)d_out, total4);
    }
}

// Round 4
// 616.326 us; speedup vs baseline: 1.3704x; 1.3704x over previous
//
#include <hip/hip_runtime.h>
#include <hip/hip_bf16.h>

// CGConv fused for MI355X (gfx950) — round 9.
//   gemm: round-5 geometry (256 thr / 4 waves / 32 edges per wave / mt=2 /
//         grid 6250, B streamed from L2) but with the register cap RELEASED:
//         launch_bounds(256,2) instead of (,3). Round-5's VGPR=84 + 96-float
//         acc proves acc sat in AGPRs and the (,3) cap left <10 spare regs,
//         so B-loads ran ~3 deep -> 71K cy/iter. Now: all 16 A-frags loaded
//         up front, 12 B-frags batched per kt ahead of the 24 MFMAs (in-order
//         vmcnt drain => 12-deep overlap), bias hoisted, rank prefetched,
//         exp2/log2/rcp epilogue. Memory-stream geometry unchanged.
//   CSR:  scatter produces inverse-perm rank[e]; gemm writes msg rows directly
//         at CSR position -> aggregate is a contiguous vectorized stream.

#define NODE_DIM 96
#define EDGE_DIM 64
#define IN_DIM   256
#define NT_TILES 12       // 192 output cols = 96 gates + 96 msgs
#define KT_TILES 8        // 256 / 32

typedef float  f32x4  __attribute__((ext_vector_type(4)));
typedef __bf16 bf16x8 __attribute__((ext_vector_type(8)));

__device__ __forceinline__ unsigned short bf16rne(float f) {
    unsigned int u = __float_as_uint(f);
    u += 0x7FFFu + ((u >> 16) & 1u);
    return (unsigned short)(u >> 16);
}

// ---------------------------------------------------------------------------
// Pack W_e/W_n (256x96 fp32 row-major) into bf16 MFMA B-fragment order.
// ---------------------------------------------------------------------------
__global__ void pack_w_kernel(const float* __restrict__ We,
                              const float* __restrict__ Wn,
                              unsigned short* __restrict__ bpack) {
    int t = blockIdx.x * blockDim.x + threadIdx.x;
    if (t >= KT_TILES * NT_TILES * 64) return;
    int tile = t >> 6, lane = t & 63;
    int kt = tile / NT_TILES, nt = tile % NT_TILES;
    const float* W = (nt < 6) ? We : Wn;
    int n  = (nt % 6) * 16 + (lane & 15);
    int k0 = kt * 32 + (lane >> 4) * 8;
    union { unsigned short u[8]; uint4 v; } tmp;
#pragma unroll
    for (int j = 0; j < 8; ++j) tmp.u[j] = bf16rne(W[(k0 + j) * NODE_DIM + n]);
    *(uint4*)(bpack + (size_t)t * 8) = tmp.v;
}

// ---------------------------------------------------------------------------
// h (N x 96 fp32) -> hb (N x 96 bf16)
// ---------------------------------------------------------------------------
__global__ void cvt_h_kernel(const float* __restrict__ h,
                             unsigned short* __restrict__ hb, int total8) {
    int i = blockIdx.x * 256 + threadIdx.x;
    if (i >= total8) return;
    const float4 v0 = ((const float4*)h)[i * 2];
    const float4 v1 = ((const float4*)h)[i * 2 + 1];
    union { unsigned short u[8]; uint4 v; } p;
    p.u[0] = bf16rne(v0.x); p.u[1] = bf16rne(v0.y);
    p.u[2] = bf16rne(v0.z); p.u[3] = bf16rne(v0.w);
    p.u[4] = bf16rne(v1.x); p.u[5] = bf16rne(v1.y);
    p.u[6] = bf16rne(v1.z); p.u[7] = bf16rne(v1.w);
    ((uint4*)hb)[i] = p.v;
}

// ---------------------------------------------------------------------------
// CSR build: histogram -> exclusive scan -> rank (inverse permutation)
// ---------------------------------------------------------------------------
__global__ void hist_kernel(const int* __restrict__ eidx, unsigned* __restrict__ deg, int E) {
    int e = blockIdx.x * 256 + threadIdx.x;
    if (e < E) atomicAdd(deg + eidx[E + e], 1u);
}

__device__ __forceinline__ unsigned block_excl_scan_256(unsigned v, int tid,
                                                        unsigned* wsum, unsigned* wpre,
                                                        unsigned* total) {
    int lane = tid & 63, w = tid >> 6;
    unsigned inc = v;
#pragma unroll
    for (int o = 1; o < 64; o <<= 1) {
        unsigned t = __shfl_up(inc, o, 64);
        if (lane >= o) inc += t;
    }
    if (lane == 63) wsum[w] = inc;
    __syncthreads();
    if (tid == 0) {
        unsigned s = 0;
#pragma unroll
        for (int k = 0; k < 4; ++k) { wpre[k] = s; s += wsum[k]; }
        *total = s;
    }
    __syncthreads();
    return inc - v + wpre[w];
}

__global__ void scan_block_kernel(const unsigned* __restrict__ deg,
                                  unsigned* __restrict__ scanned,
                                  unsigned* __restrict__ blocksum, int N) {
    __shared__ unsigned wsum[4], wpre[4], total;
    int tid = threadIdx.x;
    int i = blockIdx.x * 256 + tid;
    unsigned v = (i < N) ? deg[i] : 0u;
    unsigned excl = block_excl_scan_256(v, tid, wsum, wpre, &total);
    if (i < N) scanned[i] = excl;
    if (tid == 0) blocksum[blockIdx.x] = total;
}

__global__ void scan_sums_kernel(const unsigned* __restrict__ blocksum,
                                 unsigned* __restrict__ blockpref, int NB) {
    __shared__ unsigned wsum[4], wpre[4], total;
    int tid = threadIdx.x;
    unsigned v = (tid < NB) ? blocksum[tid] : 0u;
    unsigned excl = block_excl_scan_256(v, tid, wsum, wpre, &total);
    if (tid < NB) blockpref[tid] = excl;
}

__global__ void scan_finalize_kernel(const unsigned* __restrict__ scanned,
                                     const unsigned* __restrict__ blockpref,
                                     unsigned* __restrict__ offsets,
                                     unsigned* __restrict__ cursor, int N, int E) {
    int i = blockIdx.x * 256 + threadIdx.x;
    if (i < N) {
        unsigned o = scanned[i] + blockpref[i >> 8];
        offsets[i] = o;
        cursor[i]  = o;
    }
    if (i == 0) offsets[N] = (unsigned)E;
}

__global__ void scatter_kernel(const int* __restrict__ eidx,
                               unsigned* __restrict__ cursor,
                               unsigned* __restrict__ rank, int E) {
    int e = blockIdx.x * 256 + threadIdx.x;
    if (e < E) {
        int d = eidx[E + e];
        rank[e] = atomicAdd(cursor + d, 1u);
    }
}

// ---------------------------------------------------------------------------
// Pass B: per-edge GEMM + activation -> bf16 msg at CSR position rank[e].
// Block = 256 = 4 waves; wave handles 32 edges (mt=2). No LDS, no barriers.
// launch_bounds(256,2): ~250 regs/lane (acc in AGPRs) so loads batch deep.
// ---------------------------------------------------------------------------
__global__ __launch_bounds__(256, 2)
void gemm_msg_kernel(const unsigned short* __restrict__ hb,
                     const int*   __restrict__ eidx,
                     const float* __restrict__ ea,
                     const unsigned short* __restrict__ bpack,
                     const float* __restrict__ be,
                     const float* __restrict__ bn,
                     const unsigned* __restrict__ rank,
                     unsigned short* __restrict__ msg,
                     int E) {
    const int tid  = threadIdx.x;
    const int wave = tid >> 6, lane = tid & 63;
    const int m    = lane & 15;
    const int quad = lane >> 4;
    const int base = blockIdx.x * 128 + wave * 32;

    const unsigned short* hsq[2];
    const unsigned short* hdq[2];
    const float*          epq[2];
#pragma unroll
    for (int mt = 0; mt < 2; ++mt) {
        int e  = base + mt * 16 + m;
        int eg = (e < E) ? e : (E - 1);
        int src = eidx[eg];
        int dst = eidx[E + eg];
        hsq[mt] = hb + (size_t)src * NODE_DIM + quad * 8;
        hdq[mt] = hb + (size_t)dst * NODE_DIM + quad * 8;
        epq[mt] = ea + (size_t)eg  * EDGE_DIM + quad * 8;
    }

    // prefetch epilogue rank rows (independent loads, issued early)
    unsigned prow_[2][4];
#pragma unroll
    for (int mt = 0; mt < 2; ++mt)
#pragma unroll
        for (int r = 0; r < 4; ++r) {
            int ee = base + mt * 16 + quad * 4 + r;
            prow_[mt][r] = rank[(ee < E) ? ee : (E - 1)];
        }

    // hoist bias slices for this lane's 6 output cols
    float bev[6], bnv[6];
#pragma unroll
    for (int nt = 0; nt < 6; ++nt) {
        bev[nt] = be[nt * 16 + m];
        bnv[nt] = bn[nt * 16 + m];
    }

    // ---- load ALL 16 A-fragments up front (independent burst) ----
    bf16x8 A[2][KT_TILES];
#pragma unroll
    for (int mt = 0; mt < 2; ++mt) {
#pragma unroll
        for (int kt = 0; kt < 3; ++kt)
            A[mt][kt] = *(const bf16x8*)(hsq[mt] + kt * 32);
#pragma unroll
        for (int kt = 3; kt < 6; ++kt)
            A[mt][kt] = *(const bf16x8*)(hdq[mt] + (kt - 3) * 32);
#pragma unroll
        for (int kt = 6; kt < 8; ++kt) {
            const float4 v0 = *(const float4*)(epq[mt] + (kt - 6) * 32);
            const float4 v1 = *(const float4*)(epq[mt] + (kt - 6) * 32 + 4);
            union { unsigned short u[8]; bf16x8 b; } t;
            t.u[0] = bf16rne(v0.x); t.u[1] = bf16rne(v0.y);
            t.u[2] = bf16rne(v0.z); t.u[3] = bf16rne(v0.w);
            t.u[4] = bf16rne(v1.x); t.u[5] = bf16rne(v1.y);
            t.u[6] = bf16rne(v1.z); t.u[7] = bf16rne(v1.w);
            A[mt][kt] = t.b;
        }
    }

    f32x4 acc[2][NT_TILES];
#pragma unroll
    for (int mt = 0; mt < 2; ++mt)
#pragma unroll
        for (int nt = 0; nt < NT_TILES; ++nt) acc[mt][nt] = (f32x4){0.f, 0.f, 0.f, 0.f};

    const unsigned short* bl = bpack + lane * 8;
#pragma unroll
    for (int kt = 0; kt < KT_TILES; ++kt) {
        // batch all 12 B-frag loads for this kt before any MFMA consumes them
        bf16x8 Bf[NT_TILES];
#pragma unroll
        for (int nt = 0; nt < NT_TILES; ++nt)
            Bf[nt] = *(const bf16x8*)(bl + (kt * NT_TILES + nt) * 512);
#pragma unroll
        for (int nt = 0; nt < NT_TILES; ++nt) {
            acc[0][nt] = __builtin_amdgcn_mfma_f32_16x16x32_bf16(A[0][kt], Bf[nt], acc[0][nt], 0, 0, 0);
            acc[1][nt] = __builtin_amdgcn_mfma_f32_16x16x32_bf16(A[1][kt], Bf[nt], acc[1][nt], 0, 0, 0);
        }
    }

    // epilogue: C layout col = nt*16 + m, row-in-tile = quad*4 + r
    const float LOG2E = 1.44269504f, LN2 = 0.69314718f;
#pragma unroll
    for (int mt = 0; mt < 2; ++mt) {
#pragma unroll
        for (int r = 0; r < 4; ++r) {
            const int ee = base + mt * 16 + quad * 4 + r;
            if (ee >= E) continue;
            const size_t prow = (size_t)prow_[mt][r] * NODE_DIM;
#pragma unroll
            for (int nt = 0; nt < 6; ++nt) {
                const int col = nt * 16 + m;
                float g  = acc[mt][nt][r]     + bev[nt];
                float mm = acc[mt][nt + 6][r] + bnv[nt];
                float eg_  = __builtin_amdgcn_exp2f(-g * LOG2E);
                float gate = __builtin_amdgcn_rcpf(1.0f + eg_);
                float ae   = __builtin_amdgcn_exp2f(-fabsf(mm) * LOG2E);
                float sp   = fmaxf(mm, 0.0f) + LN2 * __builtin_amdgcn_logf(1.0f + ae);
                msg[prow + col] = bf16rne(gate * sp);
            }
        }
    }
}

// ---------------------------------------------------------------------------
// Pass C: streaming CSR reduce. Thread = (node, 8-col group): 12 threads/node,
// 16B loads, rows contiguous at offsets[n]..offsets[n+1].
// ---------------------------------------------------------------------------
__global__ __launch_bounds__(256)
void aggregate_kernel(const float* __restrict__ h,
                      const unsigned* __restrict__ offsets,
                      const unsigned short* __restrict__ msg,
                      float* __restrict__ out, int N) {
    int t = blockIdx.x * 256 + threadIdx.x;
    int n = t / 12, g = t % 12;
    if (n >= N) return;

    const unsigned o0 = offsets[n];
    const unsigned o1 = offsets[n + 1];
    const int deg = (int)(o1 - o0);

    float s0 = 0.f, s1 = 0.f, s2 = 0.f, s3 = 0.f;
    float s4 = 0.f, s5 = 0.f, s6 = 0.f, s7 = 0.f;
    for (unsigned k = o0; k < o1; ++k) {
        const uint4 v = *(const uint4*)(msg + (size_t)k * NODE_DIM + g * 8);
        s0 += __uint_as_float((v.x & 0xFFFFu) << 16);
        s1 += __uint_as_float(v.x & 0xFFFF0000u);
        s2 += __uint_as_float((v.y & 0xFFFFu) << 16);
        s3 += __uint_as_float(v.y & 0xFFFF0000u);
        s4 += __uint_as_float((v.z & 0xFFFFu) << 16);
        s5 += __uint_as_float(v.z & 0xFFFF0000u);
        s6 += __uint_as_float((v.w & 0xFFFFu) << 16);
        s7 += __uint_as_float(v.w & 0xFFFF0000u);
    }
    const float inv = 1.0f / (float)((deg > 0) ? deg : 1);
    const size_t basei = (size_t)n * NODE_DIM + g * 8;
    const float4 h0 = *(const float4*)(h + basei);
    const float4 h1 = *(const float4*)(h + basei + 4);
    float4 o0v = {h0.x + s0 * inv, h0.y + s1 * inv, h0.z + s2 * inv, h0.w + s3 * inv};
    float4 o1v = {h1.x + s4 * inv, h1.y + s5 * inv, h1.z + s6 * inv, h1.w + s7 * inv};
    *(float4*)(out + basei)     = o0v;
    *(float4*)(out + basei + 4) = o1v;
}

// ---------------------------------------------------------------------------
// Fallback (atomic path) if workspace is too small for the CSR pipeline.
// ---------------------------------------------------------------------------
#define TILE_E 64
__global__ __launch_bounds__(256, 4)
void cgconv_atomic_kernel(const float* __restrict__ h,
                          const int*   __restrict__ eidx,
                          const float* __restrict__ ea,
                          const unsigned short* __restrict__ bpack,
                          const float* __restrict__ be,
                          const float* __restrict__ bn,
                          float* __restrict__ hnew,
                          float* __restrict__ cnt,
                          int E) {
    const int tid  = threadIdx.x;
    const int wave = tid >> 6, lane = tid & 63;
    const int m    = lane & 15;
    const int quad = lane >> 4;

    const int e  = blockIdx.x * TILE_E + wave * 16 + m;
    const int eg = (e < E) ? e : (E - 1);
    const int src = eidx[eg];
    const int dst = eidx[E + eg];
    if (quad == 0 && e < E) unsafeAtomicAdd(cnt + dst, 1.0f);

    f32x4 acc[NT_TILES];
#pragma unroll
    for (int nt = 0; nt < NT_TILES; ++nt) acc[nt] = (f32x4){0.f, 0.f, 0.f, 0.f};

    const float* hsrc = h + (size_t)src * NODE_DIM;
    const float* hdst = h + (size_t)dst * NODE_DIM;
    const float* earo = ea + (size_t)eg * EDGE_DIM;

#pragma unroll
    for (int kt = 0; kt < KT_TILES; ++kt) {
        const int ko = kt * 32 + quad * 8;
        const float* p;
        if (kt < 3)      p = hsrc + ko;
        else if (kt < 6) p = hdst + (ko - NODE_DIM);
        else             p = earo + (ko - 2 * NODE_DIM);
        const float4 v0 = *(const float4*)p;
        const float4 v1 = *(const float4*)(p + 4);
        union { unsigned short u[8]; bf16x8 b; } A;
        A.u[0] = bf16rne(v0.x); A.u[1] = bf16rne(v0.y);
        A.u[2] = bf16rne(v0.z); A.u[3] = bf16rne(v0.w);
        A.u[4] = bf16rne(v1.x); A.u[5] = bf16rne(v1.y);
        A.u[6] = bf16rne(v1.z); A.u[7] = bf16rne(v1.w);
#pragma unroll
        for (int nt = 0; nt < NT_TILES; ++nt) {
            bf16x8 bfrag = *(const bf16x8*)(bpack +
                             (size_t)((kt * NT_TILES + nt) * 64 + lane) * 8);
            acc[nt] = __builtin_amdgcn_mfma_f32_16x16x32_bf16(A.b, bfrag, acc[nt], 0, 0, 0);
        }
    }

    int drow[4], erow[4];
#pragma unroll
    for (int r = 0; r < 4; ++r) {
        drow[r] = __shfl(dst, quad * 4 + r, 64);
        erow[r] = blockIdx.x * TILE_E + wave * 16 + quad * 4 + r;
    }
#pragma unroll
    for (int nt = 0; nt < 6; ++nt) {
        const int col = nt * 16 + m;
        const float bev = be[col];
        const float bnv = bn[col];
#pragma unroll
        for (int r = 0; r < 4; ++r) {
            if (erow[r] >= E) continue;
            float g  = acc[nt][r] + bev;
            float mm = acc[nt + 6][r] + bnv;
            float gate = 1.0f / (1.0f + __expf(-g));
            float sp   = fmaxf(mm, 0.0f) + __logf(1.0f + __expf(-fabsf(mm)));
            unsafeAtomicAdd(hnew + (size_t)drow[r] * NODE_DIM + col, gate * sp);
        }
    }
}

__global__ void finalize_kernel(const float* __restrict__ h,
                                const float* __restrict__ hnew,
                                const float* __restrict__ cnt,
                                float* __restrict__ out,
                                int total4) {
    int i = blockIdx.x * blockDim.x + threadIdx.x;
    if (i >= total4) return;
    int n = i / 24;
    float inv = 1.0f / fmaxf(cnt[n], 1.0f);
    float4 hv = ((const float4*)h)[i];
    float4 av = ((const float4*)hnew)[i];
    float4 o = {hv.x + av.x * inv, hv.y + av.y * inv, hv.z + av.z * inv, hv.w + av.w * inv};
    ((float4*)out)[i] = o;
}

// ---------------------------------------------------------------------------
extern "C" void kernel_launch(void* const* d_in, const int* in_sizes, int n_in,
                              void* d_out, int out_size, void* d_ws, size_t ws_size,
                              hipStream_t stream) {
    const float* h   = (const float*)d_in[0];
    const int*   ei  = (const int*)  d_in[1];
    const float* ea  = (const float*)d_in[2];
    const float* We  = (const float*)d_in[3];
    const float* be  = (const float*)d_in[4];
    const float* Wn  = (const float*)d_in[5];
    const float* bn  = (const float*)d_in[6];

    const int N = in_sizes[0] / NODE_DIM;     // 50000
    const int E = in_sizes[2] / EDGE_DIM;     // 800000
    char* ws = (char*)d_ws;

    size_t off = 0;
    auto take = [&](size_t bytes) { size_t o = off; off = (off + bytes + 511) & ~(size_t)511; return o; };
    const size_t O_BPACK  = take((size_t)KT_TILES * NT_TILES * 64 * 16);   // 96 KB
    const size_t O_DEG    = take((size_t)N * 4);
    const size_t O_SCAN   = take((size_t)N * 4);
    const size_t O_BSUM   = take(1024);
    const size_t O_BPREF  = take(1024);
    const size_t O_OFFS   = take((size_t)(N + 1) * 4);
    const size_t O_CURS   = take((size_t)N * 4);
    const size_t O_RANK   = take((size_t)E * 4);
    const size_t O_HB     = take((size_t)N * NODE_DIM * 2);               // 9.6 MB
    const size_t O_MSG    = take((size_t)E * NODE_DIM * 2);               // 153.6 MB
    const size_t NEED = off;

    unsigned short* bpack = (unsigned short*)(ws + O_BPACK);
    pack_w_kernel<<<(KT_TILES * NT_TILES * 64 + 255) / 256, 256, 0, stream>>>(We, Wn, bpack);

    if (ws_size >= NEED) {
        unsigned* deg    = (unsigned*)(ws + O_DEG);
        unsigned* scn    = (unsigned*)(ws + O_SCAN);
        unsigned* bsum   = (unsigned*)(ws + O_BSUM);
        unsigned* bpref  = (unsigned*)(ws + O_BPREF);
        unsigned* offs   = (unsigned*)(ws + O_OFFS);
        unsigned* curs   = (unsigned*)(ws + O_CURS);
        unsigned* rank   = (unsigned*)(ws + O_RANK);
        unsigned short* hb  = (unsigned short*)(ws + O_HB);
        unsigned short* msg = (unsigned short*)(ws + O_MSG);

        hipMemsetAsync(deg, 0, (size_t)N * 4, stream);

        const int total8 = N * NODE_DIM / 8;   // 600000
        cvt_h_kernel<<<(total8 + 255) / 256, 256, 0, stream>>>(h, hb, total8);

        const int NB = (N + 255) / 256;
        hist_kernel<<<(E + 255) / 256, 256, 0, stream>>>(ei, deg, E);
        scan_block_kernel<<<NB, 256, 0, stream>>>(deg, scn, bsum, N);
        scan_sums_kernel<<<1, 256, 0, stream>>>(bsum, bpref, NB);
        scan_finalize_kernel<<<NB, 256, 0, stream>>>(scn, bpref, offs, curs, N, E);
        scatter_kernel<<<(E + 255) / 256, 256, 0, stream>>>(ei, curs, rank, E);

        gemm_msg_kernel<<<(E + 127) / 128, 256, 0, stream>>>(hb, ei, ea, bpack, be, bn, rank, msg, E);

        const int aggthreads = N * 12;
        aggregate_kernel<<<(aggthreads + 255) / 256, 256, 0, stream>>>(h, offs, msg, (float*)d_out, N);
    } else {
        size_t cnt_off  = O_DEG;
        size_t hnew_off = (cnt_off + (size_t)N * 4 + 511) & ~(size_t)511;
        float* cnt  = (float*)(ws + cnt_off);
        float* hnew = (float*)(ws + hnew_off);
        hipMemsetAsync(ws + cnt_off, 0, hnew_off - cnt_off + (size_t)N * NODE_DIM * 4, stream);
        cgconv_atomic_kernel<<<(E + TILE_E - 1) / TILE_E, 256, 0, stream>>>(
            h, ei, ea, bpack, be, bn, hnew, cnt, E);
        const int total4 = N * (NODE_DIM / 4);
        finalize_kernel<<<(total4 + 255) / 256, 256, 0, stream>>>(h, hnew, cnt, (float*)d_out, total4);
    }
}

// Round 5
// 604.907 us; speedup vs baseline: 1.3963x; 1.0189x over previous
//
#include <hip/hip_runtime.h>
#include <hip/hip_bf16.h>

// CGConv fused for MI355X (gfx950) — round 10.
//   gemm: wave-pair structure. Block = 4 waves / 128 edges (round-5 window
//         preserved). A wave-pair shares 64 edges (mt=4); each wave of the
//         pair owns HALF the output cols (3 gate+msg tile-pairs). Per kt:
//         6 B-loads feed 24 MFMAs (4 MFMA/B-frag, 2x round 5), B-stream
//         halves to 1.2 GB, and per-wave load count drops 96->48 so the
//         allocator's natural batching covers 2x work per exposed latency.
//         Rounds 7-9 proved the compiler won't hold big fragment arrays
//         (VGPR came back 76-92 regardless of source-level hoisting), so
//         this shrinks the work statement instead of fighting the allocator.
//   tail: launches fused 12->7 (pack+cvt+hist in one prep kernel; scan_sums+
//         finalize merged: each block reduces blocksum[0..bid) itself).
//         Tail was rigid at ~345 us across rounds 5-9.
//   CSR:  scatter produces inverse-perm rank[e]; gemm writes msg rows directly
//         at CSR position -> aggregate is a contiguous vectorized stream.

#define NODE_DIM 96
#define EDGE_DIM 64
#define IN_DIM   256
#define NT_TILES 12       // 192 output cols = 96 gates + 96 msgs
#define KT_TILES 8        // 256 / 32
#define PACK_TOTAL (KT_TILES * NT_TILES * 64)

typedef float  f32x4  __attribute__((ext_vector_type(4)));
typedef __bf16 bf16x8 __attribute__((ext_vector_type(8)));

__device__ __forceinline__ unsigned short bf16rne(float f) {
    unsigned int u = __float_as_uint(f);
    u += 0x7FFFu + ((u >> 16) & 1u);
    return (unsigned short)(u >> 16);
}

// ---------------------------------------------------------------------------
// Fused prep: pack W (6144 threads) + cvt h->bf16 (600K) + degree hist (800K).
// All three are independent; deg is zeroed by the preceding memset.
// ---------------------------------------------------------------------------
__global__ void prep_kernel(const float* __restrict__ We,
                            const float* __restrict__ Wn,
                            unsigned short* __restrict__ bpack,
                            const float* __restrict__ h,
                            unsigned short* __restrict__ hb, int total8,
                            const int* __restrict__ eidx,
                            unsigned* __restrict__ deg, int E) {
    int t = blockIdx.x * 256 + threadIdx.x;
    if (t < PACK_TOTAL) {
        int tile = t >> 6, lane = t & 63;
        int kt = tile / NT_TILES, nt = tile % NT_TILES;
        const float* W = (nt < 6) ? We : Wn;
        int n  = (nt % 6) * 16 + (lane & 15);
        int k0 = kt * 32 + (lane >> 4) * 8;
        union { unsigned short u[8]; uint4 v; } tmp;
#pragma unroll
        for (int j = 0; j < 8; ++j) tmp.u[j] = bf16rne(W[(k0 + j) * NODE_DIM + n]);
        *(uint4*)(bpack + (size_t)t * 8) = tmp.v;
    }
    if (t < total8) {
        const float4 v0 = ((const float4*)h)[t * 2];
        const float4 v1 = ((const float4*)h)[t * 2 + 1];
        union { unsigned short u[8]; uint4 v; } p;
        p.u[0] = bf16rne(v0.x); p.u[1] = bf16rne(v0.y);
        p.u[2] = bf16rne(v0.z); p.u[3] = bf16rne(v0.w);
        p.u[4] = bf16rne(v1.x); p.u[5] = bf16rne(v1.y);
        p.u[6] = bf16rne(v1.z); p.u[7] = bf16rne(v1.w);
        ((uint4*)hb)[t] = p.v;
    }
    if (t < E) atomicAdd(deg + eidx[E + t], 1u);
}

// ---------------------------------------------------------------------------
// Standalone pack (fallback path only).
// ---------------------------------------------------------------------------
__global__ void pack_w_kernel(const float* __restrict__ We,
                              const float* __restrict__ Wn,
                              unsigned short* __restrict__ bpack) {
    int t = blockIdx.x * blockDim.x + threadIdx.x;
    if (t >= PACK_TOTAL) return;
    int tile = t >> 6, lane = t & 63;
    int kt = tile / NT_TILES, nt = tile % NT_TILES;
    const float* W = (nt < 6) ? We : Wn;
    int n  = (nt % 6) * 16 + (lane & 15);
    int k0 = kt * 32 + (lane >> 4) * 8;
    union { unsigned short u[8]; uint4 v; } tmp;
#pragma unroll
    for (int j = 0; j < 8; ++j) tmp.u[j] = bf16rne(W[(k0 + j) * NODE_DIM + n]);
    *(uint4*)(bpack + (size_t)t * 8) = tmp.v;
}

// ---------------------------------------------------------------------------
// CSR scan: per-block exclusive scan -> (scanned, blocksum)
// ---------------------------------------------------------------------------
__device__ __forceinline__ unsigned block_excl_scan_256(unsigned v, int tid,
                                                        unsigned* wsum, unsigned* wpre,
                                                        unsigned* total) {
    int lane = tid & 63, w = tid >> 6;
    unsigned inc = v;
#pragma unroll
    for (int o = 1; o < 64; o <<= 1) {
        unsigned t = __shfl_up(inc, o, 64);
        if (lane >= o) inc += t;
    }
    if (lane == 63) wsum[w] = inc;
    __syncthreads();
    if (tid == 0) {
        unsigned s = 0;
#pragma unroll
        for (int k = 0; k < 4; ++k) { wpre[k] = s; s += wsum[k]; }
        *total = s;
    }
    __syncthreads();
    return inc - v + wpre[w];
}

__global__ void scan_block_kernel(const unsigned* __restrict__ deg,
                                  unsigned* __restrict__ scanned,
                                  unsigned* __restrict__ blocksum, int N) {
    __shared__ unsigned wsum[4], wpre[4], total;
    int tid = threadIdx.x;
    int i = blockIdx.x * 256 + tid;
    unsigned v = (i < N) ? deg[i] : 0u;
    unsigned excl = block_excl_scan_256(v, tid, wsum, wpre, &total);
    if (i < N) scanned[i] = excl;
    if (tid == 0) blocksum[blockIdx.x] = total;
}

// ---------------------------------------------------------------------------
// Fused finalize: each block reduces blocksum[0..bid) itself (NB ~196, cheap),
// then writes offsets/cursor. Replaces scan_sums + scan_finalize.
// ---------------------------------------------------------------------------
__global__ void scan_finalize2_kernel(const unsigned* __restrict__ scanned,
                                      const unsigned* __restrict__ blocksum,
                                      unsigned* __restrict__ offsets,
                                      unsigned* __restrict__ cursor,
                                      int N, int E, int NB) {
    __shared__ unsigned wtot[4];
    const int tid = threadIdx.x, bid = blockIdx.x;
    const int lane = tid & 63, w = tid >> 6;
    unsigned v = 0;
    for (int j = tid; j < bid; j += 256) v += blocksum[j];
#pragma unroll
    for (int o = 1; o < 64; o <<= 1) v += __shfl_xor(v, o, 64);
    if (lane == 0) wtot[w] = v;
    __syncthreads();
    const unsigned bpref = wtot[0] + wtot[1] + wtot[2] + wtot[3];
    const int i = bid * 256 + tid;
    if (i < N) {
        unsigned o = scanned[i] + bpref;
        offsets[i] = o;
        cursor[i]  = o;
    }
    if (i == 0) offsets[N] = (unsigned)E;
}

__global__ void scatter_kernel(const int* __restrict__ eidx,
                               unsigned* __restrict__ cursor,
                               unsigned* __restrict__ rank, int E) {
    int e = blockIdx.x * 256 + threadIdx.x;
    if (e < E) {
        int d = eidx[E + e];
        rank[e] = atomicAdd(cursor + d, 1u);
    }
}

// ---------------------------------------------------------------------------
// Pass B: per-edge GEMM + activation -> bf16 msg at CSR position rank[e].
// Block = 256 = 4 waves = 2 wave-pairs. Pair wp handles 64 edges (mt=4);
// wave `half` of the pair owns 3 gate+msg tile-pairs (cols half*48..+47).
// Per kt: 4 A-loads + 6 B-loads -> 24 MFMAs. No LDS, no barriers.
// ---------------------------------------------------------------------------
__global__ __launch_bounds__(256, 2)
void gemm_msg_kernel(const unsigned short* __restrict__ hb,
                     const int*   __restrict__ eidx,
                     const float* __restrict__ ea,
                     const unsigned short* __restrict__ bpack,
                     const float* __restrict__ be,
                     const float* __restrict__ bn,
                     const unsigned* __restrict__ rank,
                     unsigned short* __restrict__ msg,
                     int E) {
    const int tid  = threadIdx.x;
    const int wave = tid >> 6, lane = tid & 63;
    const int wp   = wave >> 1;       // wave-pair: which 64-edge group
    const int half = wave & 1;        // which col-half (3 tile-pairs)
    const int m    = lane & 15;
    const int quad = lane >> 4;
    const int base = blockIdx.x * 128 + wp * 64;

    const unsigned short* hsq[4];
    const unsigned short* hdq[4];
    const float*          epq[4];
#pragma unroll
    for (int mt = 0; mt < 4; ++mt) {
        int e  = base + mt * 16 + m;
        int eg = (e < E) ? e : (E - 1);
        int src = eidx[eg];
        int dst = eidx[E + eg];
        hsq[mt] = hb + (size_t)src * NODE_DIM + quad * 8;
        hdq[mt] = hb + (size_t)dst * NODE_DIM + quad * 8;
        epq[mt] = ea + (size_t)eg  * EDGE_DIM + quad * 8;
    }

    // prefetch epilogue rank rows (independent loads)
    unsigned prow_[4][4];
#pragma unroll
    for (int mt = 0; mt < 4; ++mt)
#pragma unroll
        for (int r = 0; r < 4; ++r) {
            int ee = base + mt * 16 + quad * 4 + r;
            prow_[mt][r] = rank[(ee < E) ? ee : (E - 1)];
        }

    // bias for this wave's 3 col-tiles
    float bev[3], bnv[3];
#pragma unroll
    for (int p = 0; p < 3; ++p) {
        bev[p] = be[half * 48 + p * 16 + m];
        bnv[p] = bn[half * 48 + p * 16 + m];
    }

    f32x4 accg[4][3], accm[4][3];
#pragma unroll
    for (int mt = 0; mt < 4; ++mt)
#pragma unroll
        for (int p = 0; p < 3; ++p) {
            accg[mt][p] = (f32x4){0.f, 0.f, 0.f, 0.f};
            accm[mt][p] = (f32x4){0.f, 0.f, 0.f, 0.f};
        }

    const unsigned short* bl = bpack + lane * 8;
#pragma unroll
    for (int kt = 0; kt < KT_TILES; ++kt) {
        // 6 B-frag loads for this kt (this wave's col-half)
        bf16x8 Bg[3], Bm[3];
#pragma unroll
        for (int p = 0; p < 3; ++p) {
            Bg[p] = *(const bf16x8*)(bl + (kt * NT_TILES + half * 3 + p) * 512);
            Bm[p] = *(const bf16x8*)(bl + (kt * NT_TILES + 6 + half * 3 + p) * 512);
        }
        // 4 A-frag loads
        bf16x8 A[4];
#pragma unroll
        for (int mt = 0; mt < 4; ++mt) {
            if (kt < 3) {
                A[mt] = *(const bf16x8*)(hsq[mt] + kt * 32);
            } else if (kt < 6) {
                A[mt] = *(const bf16x8*)(hdq[mt] + (kt - 3) * 32);
            } else {
                const float4 v0 = *(const float4*)(epq[mt] + (kt - 6) * 32);
                const float4 v1 = *(const float4*)(epq[mt] + (kt - 6) * 32 + 4);
                union { unsigned short u[8]; bf16x8 b; } t;
                t.u[0] = bf16rne(v0.x); t.u[1] = bf16rne(v0.y);
                t.u[2] = bf16rne(v0.z); t.u[3] = bf16rne(v0.w);
                t.u[4] = bf16rne(v1.x); t.u[5] = bf16rne(v1.y);
                t.u[6] = bf16rne(v1.z); t.u[7] = bf16rne(v1.w);
                A[mt] = t.b;
            }
        }
        // 24 MFMAs: 4 per B-frag
#pragma unroll
        for (int p = 0; p < 3; ++p)
#pragma unroll
            for (int mt = 0; mt < 4; ++mt) {
                accg[mt][p] = __builtin_amdgcn_mfma_f32_16x16x32_bf16(A[mt], Bg[p], accg[mt][p], 0, 0, 0);
                accm[mt][p] = __builtin_amdgcn_mfma_f32_16x16x32_bf16(A[mt], Bm[p], accm[mt][p], 0, 0, 0);
            }
    }

    // epilogue: C layout col = tile*16 + m, row-in-tile = quad*4 + r
    const float LOG2E = 1.44269504f, LN2 = 0.69314718f;
#pragma unroll
    for (int mt = 0; mt < 4; ++mt) {
#pragma unroll
        for (int r = 0; r < 4; ++r) {
            const int ee = base + mt * 16 + quad * 4 + r;
            if (ee >= E) continue;
            const size_t prow = (size_t)prow_[mt][r] * NODE_DIM;
#pragma unroll
            for (int p = 0; p < 3; ++p) {
                const int col = half * 48 + p * 16 + m;
                float g  = accg[mt][p][r] + bev[p];
                float mm = accm[mt][p][r] + bnv[p];
                float eg_  = __builtin_amdgcn_exp2f(-g * LOG2E);
                float gate = __builtin_amdgcn_rcpf(1.0f + eg_);
                float ae   = __builtin_amdgcn_exp2f(-fabsf(mm) * LOG2E);
                float sp   = fmaxf(mm, 0.0f) + LN2 * __builtin_amdgcn_logf(1.0f + ae);
                msg[prow + col] = bf16rne(gate * sp);
            }
        }
    }
}

// ---------------------------------------------------------------------------
// Pass C: streaming CSR reduce. Thread = (node, 8-col group): 12 threads/node,
// 16B loads, rows contiguous at offsets[n]..offsets[n+1].
// ---------------------------------------------------------------------------
__global__ __launch_bounds__(256)
void aggregate_kernel(const float* __restrict__ h,
                      const unsigned* __restrict__ offsets,
                      const unsigned short* __restrict__ msg,
                      float* __restrict__ out, int N) {
    int t = blockIdx.x * 256 + threadIdx.x;
    int n = t / 12, g = t % 12;
    if (n >= N) return;

    const unsigned o0 = offsets[n];
    const unsigned o1 = offsets[n + 1];
    const int deg = (int)(o1 - o0);

    float s0 = 0.f, s1 = 0.f, s2 = 0.f, s3 = 0.f;
    float s4 = 0.f, s5 = 0.f, s6 = 0.f, s7 = 0.f;
    for (unsigned k = o0; k < o1; ++k) {
        const uint4 v = *(const uint4*)(msg + (size_t)k * NODE_DIM + g * 8);
        s0 += __uint_as_float((v.x & 0xFFFFu) << 16);
        s1 += __uint_as_float(v.x & 0xFFFF0000u);
        s2 += __uint_as_float((v.y & 0xFFFFu) << 16);
        s3 += __uint_as_float(v.y & 0xFFFF0000u);
        s4 += __uint_as_float((v.z & 0xFFFFu) << 16);
        s5 += __uint_as_float(v.z & 0xFFFF0000u);
        s6 += __uint_as_float((v.w & 0xFFFFu) << 16);
        s7 += __uint_as_float(v.w & 0xFFFF0000u);
    }
    const float inv = 1.0f / (float)((deg > 0) ? deg : 1);
    const size_t basei = (size_t)n * NODE_DIM + g * 8;
    const float4 h0 = *(const float4*)(h + basei);
    const float4 h1 = *(const float4*)(h + basei + 4);
    float4 o0v = {h0.x + s0 * inv, h0.y + s1 * inv, h0.z + s2 * inv, h0.w + s3 * inv};
    float4 o1v = {h1.x + s4 * inv, h1.y + s5 * inv, h1.z + s6 * inv, h1.w + s7 * inv};
    *(float4*)(out + basei)     = o0v;
    *(float4*)(out + basei + 4) = o1v;
}

// ---------------------------------------------------------------------------
// Fallback (atomic path) if workspace is too small for the CSR pipeline.
// ---------------------------------------------------------------------------
#define TILE_E 64
__global__ __launch_bounds__(256, 4)
void cgconv_atomic_kernel(const float* __restrict__ h,
                          const int*   __restrict__ eidx,
                          const float* __restrict__ ea,
                          const unsigned short* __restrict__ bpack,
                          const float* __restrict__ be,
                          const float* __restrict__ bn,
                          float* __restrict__ hnew,
                          float* __restrict__ cnt,
                          int E) {
    const int tid  = threadIdx.x;
    const int wave = tid >> 6, lane = tid & 63;
    const int m    = lane & 15;
    const int quad = lane >> 4;

    const int e  = blockIdx.x * TILE_E + wave * 16 + m;
    const int eg = (e < E) ? e : (E - 1);
    const int src = eidx[eg];
    const int dst = eidx[E + eg];
    if (quad == 0 && e < E) unsafeAtomicAdd(cnt + dst, 1.0f);

    f32x4 acc[NT_TILES];
#pragma unroll
    for (int nt = 0; nt < NT_TILES; ++nt) acc[nt] = (f32x4){0.f, 0.f, 0.f, 0.f};

    const float* hsrc = h + (size_t)src * NODE_DIM;
    const float* hdst = h + (size_t)dst * NODE_DIM;
    const float* earo = ea + (size_t)eg * EDGE_DIM;

#pragma unroll
    for (int kt = 0; kt < KT_TILES; ++kt) {
        const int ko = kt * 32 + quad * 8;
        const float* p;
        if (kt < 3)      p = hsrc + ko;
        else if (kt < 6) p = hdst + (ko - NODE_DIM);
        else             p = earo + (ko - 2 * NODE_DIM);
        const float4 v0 = *(const float4*)p;
        const float4 v1 = *(const float4*)(p + 4);
        union { unsigned short u[8]; bf16x8 b; } A;
        A.u[0] = bf16rne(v0.x); A.u[1] = bf16rne(v0.y);
        A.u[2] = bf16rne(v0.z); A.u[3] = bf16rne(v0.w);
        A.u[4] = bf16rne(v1.x); A.u[5] = bf16rne(v1.y);
        A.u[6] = bf16rne(v1.z); A.u[7] = bf16rne(v1.w);
#pragma unroll
        for (int nt = 0; nt < NT_TILES; ++nt) {
            bf16x8 bfrag = *(const bf16x8*)(bpack +
                             (size_t)((kt * NT_TILES + nt) * 64 + lane) * 8);
            acc[nt] = __builtin_amdgcn_mfma_f32_16x16x32_bf16(A.b, bfrag, acc[nt], 0, 0, 0);
        }
    }

    int drow[4], erow[4];
#pragma unroll
    for (int r = 0; r < 4; ++r) {
        drow[r] = __shfl(dst, quad * 4 + r, 64);
        erow[r] = blockIdx.x * TILE_E + wave * 16 + quad * 4 + r;
    }
#pragma unroll
    for (int nt = 0; nt < 6; ++nt) {
        const int col = nt * 16 + m;
        const float bev = be[col];
        const float bnv = bn[col];
#pragma unroll
        for (int r = 0; r < 4; ++r) {
            if (erow[r] >= E) continue;
            float g  = acc[nt][r] + bev;
            float mm = acc[nt + 6][r] + bnv;
            float gate = 1.0f / (1.0f + __expf(-g));
            float sp   = fmaxf(mm, 0.0f) + __logf(1.0f + __expf(-fabsf(mm)));
            unsafeAtomicAdd(hnew + (size_t)drow[r] * NODE_DIM + col, gate * sp);
        }
    }
}

__global__ void finalize_kernel(const float* __restrict__ h,
                                const float* __restrict__ hnew,
                                const float* __restrict__ cnt,
                                float* __restrict__ out,
                                int total4) {
    int i = blockIdx.x * blockDim.x + threadIdx.x;
    if (i >= total4) return;
    int n = i / 24;
    float inv = 1.0f / fmaxf(cnt[n], 1.0f);
    float4 hv = ((const float4*)h)[i];
    float4 av = ((const float4*)hnew)[i];
    float4 o = {hv.x + av.x * inv, hv.y + av.y * inv, hv.z + av.z * inv, hv.w + av.w * inv};
    ((float4*)out)[i] = o;
}

// ---------------------------------------------------------------------------
extern "C" void kernel_launch(void* const* d_in, const int* in_sizes, int n_in,
                              void* d_out, int out_size, void* d_ws, size_t ws_size,
                              hipStream_t stream) {
    const float* h   = (const float*)d_in[0];
    const int*   ei  = (const int*)  d_in[1];
    const float* ea  = (const float*)d_in[2];
    const float* We  = (const float*)d_in[3];
    const float* be  = (const float*)d_in[4];
    const float* Wn  = (const float*)d_in[5];
    const float* bn  = (const float*)d_in[6];

    const int N = in_sizes[0] / NODE_DIM;     // 50000
    const int E = in_sizes[2] / EDGE_DIM;     // 800000
    char* ws = (char*)d_ws;

    size_t off = 0;
    auto take = [&](size_t bytes) { size_t o = off; off = (off + bytes + 511) & ~(size_t)511; return o; };
    const size_t O_BPACK  = take((size_t)PACK_TOTAL * 16);                 // 96 KB
    const size_t O_DEG    = take((size_t)N * 4);
    const size_t O_SCAN   = take((size_t)N * 4);
    const size_t O_BSUM   = take(4096);
    const size_t O_OFFS   = take((size_t)(N + 1) * 4);
    const size_t O_CURS   = take((size_t)N * 4);
    const size_t O_RANK   = take((size_t)E * 4);
    const size_t O_HB     = take((size_t)N * NODE_DIM * 2);               // 9.6 MB
    const size_t O_MSG    = take((size_t)E * NODE_DIM * 2);               // 153.6 MB
    const size_t NEED = off;

    unsigned short* bpack = (unsigned short*)(ws + O_BPACK);

    if (ws_size >= NEED) {
        unsigned* deg    = (unsigned*)(ws + O_DEG);
        unsigned* scn    = (unsigned*)(ws + O_SCAN);
        unsigned* bsum   = (unsigned*)(ws + O_BSUM);
        unsigned* offs   = (unsigned*)(ws + O_OFFS);
        unsigned* curs   = (unsigned*)(ws + O_CURS);
        unsigned* rank   = (unsigned*)(ws + O_RANK);
        unsigned short* hb  = (unsigned short*)(ws + O_HB);
        unsigned short* msg = (unsigned short*)(ws + O_MSG);

        hipMemsetAsync(deg, 0, (size_t)N * 4, stream);

        const int total8 = N * NODE_DIM / 8;   // 600000
        const int NB = (N + 255) / 256;

        // fused: pack_w + cvt_h + hist (grid covers the largest of the three)
        int prep_threads = E;
        if (total8 > prep_threads) prep_threads = total8;
        if (PACK_TOTAL > prep_threads) prep_threads = PACK_TOTAL;
        prep_kernel<<<(prep_threads + 255) / 256, 256, 0, stream>>>(
            We, Wn, bpack, h, hb, total8, ei, deg, E);

        scan_block_kernel<<<NB, 256, 0, stream>>>(deg, scn, bsum, N);
        scan_finalize2_kernel<<<NB, 256, 0, stream>>>(scn, bsum, offs, curs, N, E, NB);
        scatter_kernel<<<(E + 255) / 256, 256, 0, stream>>>(ei, curs, rank, E);

        gemm_msg_kernel<<<(E + 127) / 128, 256, 0, stream>>>(hb, ei, ea, bpack, be, bn, rank, msg, E);

        const int aggthreads = N * 12;
        aggregate_kernel<<<(aggthreads + 255) / 256, 256, 0, stream>>>(h, offs, msg, (float*)d_out, N);
    } else {
        pack_w_kernel<<<(PACK_TOTAL + 255) / 256, 256, 0, stream>>>(We, Wn, bpack);
        size_t cnt_off  = O_DEG;
        size_t hnew_off = (cnt_off + (size_t)N * 4 + 511) & ~(size_t)511;
        float* cnt  = (float*)(ws + cnt_off);
        float* hnew = (float*)(ws + hnew_off);
        hipMemsetAsync(ws + cnt_off, 0, hnew_off - cnt_off + (size_t)N * NODE_DIM * 4, stream);
        cgconv_atomic_kernel<<<(E + TILE_E - 1) / TILE_E, 256, 0, stream>>>(
            h, ei, ea, bpack, be, bn, hnew, cnt, E);
        const int total4 = N * (NODE_DIM / 4);
        finalize_kernel<<<(total4 + 255) / 256, 256, 0, stream>>>(h, hnew, cnt, (float*)d_out, total4);
    }
}